// Round 21
// baseline (126.379 us; speedup 1.0000x reference)
//
#include <hip/hip_runtime.h>
#include <stdint.h>

#define T_STEPS 512
#define BATCH   512
#define IN_DIM  128
#define GDIM    32   // 4 gates x 8 qubits
#define SLICE   (BATCH * GDIM)   // 16384 floats per time step
#define INV2PI  0.15915494309189535f

typedef float f4 __attribute__((ext_vector_type(4)));

// ---------------------------------------------------------------------------
// DPP helpers. Conventions PROVEN by passing kernels (r2/r8/r11/r13/r17):
//   row_shl:k (0x100|k): dst i <- src i+k (OOB -> 0 with bound_ctrl=1)
//   row_shr:k (0x110|k): dst i <- src i-k
//   row_ror:8 (0x128):   dst i <- src (i+8)&15   (symmetric at 8)
//   row_mirror 0x140: dst i <- src 15-i ; row_half_mirror 0x141: i^7 within 8.
//   quad_perm 0xB1: pair swap (dst i <- src i^1).
// ---------------------------------------------------------------------------
template <int CTRL>
__device__ __forceinline__ float dppm(float x) {
    return __int_as_float(__builtin_amdgcn_mov_dpp(__float_as_int(x), CTRL, 0xF, 0xF, true));
}
template <int CTRL>
__device__ __forceinline__ float dppk(float old, float x) {
    return __int_as_float(__builtin_amdgcn_update_dpp(
        __float_as_int(old), __float_as_int(x), CTRL, 0xF, 0xF, false));
}

// tanh Pade[5/4]: x(945+105u+u^2)/(945+420u+15u^2), u=x^2. err<=5e-5 on [-2.2,2.2].
__device__ __forceinline__ float tanh_pade(float x) {
    float u = x * x;
    float n = fmaf(u, u + 105.0f, 945.0f);
    float d = fmaf(u, fmaf(u, 15.0f, 420.0f), 945.0f);
    return (x * n) * __builtin_amdgcn_rcpf(d);
}

// async global->LDS, 16 bytes per lane: LDS dest = base + lane*16
__device__ __forceinline__ void gload_lds16(const float* g, float* l) {
    __builtin_amdgcn_global_load_lds(
        (const __attribute__((address_space(1))) void*)g,
        (__attribute__((address_space(3))) void*)l, 16, 0, 0);
}

// ---------------------------------------------------------------------------
// Kernel 1: X[row][g] = (inp[row].W_gate[:,q] + b_gate[q] + theta_gate[q])/2pi
// K-SPLIT producer/consumer: one 64-row tile per block, K halved (2 x 64 cols)
// -> LDS 2x64x66 = 33.8KB -> 4 blocks/CU (was 2). Grid 4096: ~4x block
// turnover decorrelates block phases so one block's compute overlays
// another's HBM streaming (r20's 2 phase-locked blocks left ~11us of idle
// memory windows: 38.5us vs 26.6 BW floor).
// Producers (tid<256) issue ALL 8 f4 loads up-front (half1 stays in flight
// across the first barrier), write half0, sync, write half1 while consumers
// (4 waves, wave=gate, r13-proven body) chew half0; sync; chew half1 + store.
// Pad 66: float2 consumer reads are 4-way (cheap, LDS pipe not critical).
// ---------------------------------------------------------------------------
__global__ __launch_bounds__(512) void qlstm_xproj(
    const float* __restrict__ inp,
    const float* __restrict__ Wf, const float* __restrict__ bf,
    const float* __restrict__ Wi, const float* __restrict__ bi,
    const float* __restrict__ Wu, const float* __restrict__ bu,
    const float* __restrict__ Wo, const float* __restrict__ bo,
    const float* __restrict__ thf, const float* __restrict__ thi,
    const float* __restrict__ thu, const float* __restrict__ tho,
    float* __restrict__ X)
{
    __shared__ float tile[2][64 * 66];       // 33.8 KB -> 4 blocks/CU
    const int tid = threadIdx.x;
    const long long row0 = (long long)blockIdx.x * 64;
    const bool producer = (tid < 256);

    f4 v0[4], v1[4];
    if (producer) {
        // issue all 8 loads now; v1's stay in flight across the first barrier
        #pragma unroll
        for (int j = 0; j < 4; ++j) {
            int f = tid + j * 256;           // 0..1023
            int r = f >> 4, c16 = f & 15;    // row, 16B-chunk within 64 floats
            const float* rb = inp + (row0 + r) * IN_DIM;
            v0[j] = __builtin_nontemporal_load((const f4*)rb + c16);
            v1[j] = __builtin_nontemporal_load((const f4*)(rb + 64) + c16);
        }
        // write half 0
        #pragma unroll
        for (int j = 0; j < 4; ++j) {
            int f = tid + j * 256;
            int r = f >> 4, c16 = f & 15;
            float* d = &tile[0][r * 66 + c16 * 4];
            d[0] = v0[j].x; d[1] = v0[j].y; d[2] = v0[j].z; d[3] = v0[j].w;
        }
    }

    // consumer setup
    const int c0 = tid - 256;
    const int g  = __builtin_amdgcn_readfirstlane(c0 >> 6) & 3;  // wave = gate
    const int rl = c0 & 63;
    const float* W  = (g == 0) ? Wf : (g == 1) ? Wi : (g == 2) ? Wu : Wo;
    const float* B  = (g == 0) ? bf : (g == 1) ? bi : (g == 2) ? bu : bo;
    const float* TH = (g == 0) ? thf : (g == 1) ? thi : (g == 2) ? thu : tho;

    float acc[8];
    #pragma unroll
    for (int j = 0; j < 8; ++j) acc[j] = B[j] + TH[j];

    __syncthreads();                         // half 0 ready

    if (producer) {
        // write half 1 (vmcnt waits land here, overlapped w/ consumer compute)
        #pragma unroll
        for (int j = 0; j < 4; ++j) {
            int f = tid + j * 256;
            int r = f >> 4, c16 = f & 15;
            float* d = &tile[1][r * 66 + c16 * 4];
            d[0] = v1[j].x; d[1] = v1[j].y; d[2] = v1[j].z; d[3] = v1[j].w;
        }
    } else {
        const float2* trow = (const float2*)&tile[0][rl * 66];
        #pragma unroll 8
        for (int k2 = 0; k2 < 32; ++k2) {
            float2 v = trow[k2];
            int k = 2 * k2;
            #pragma unroll
            for (int j = 0; j < 8; ++j) {
                acc[j] = fmaf(v.x, W[k * 8 + j], acc[j]);        // uniform -> s_load
                acc[j] = fmaf(v.y, W[(k + 1) * 8 + j], acc[j]);
            }
        }
    }

    __syncthreads();                         // half 1 ready

    if (!producer) {
        const float2* trow = (const float2*)&tile[1][rl * 66];
        #pragma unroll 8
        for (int k2 = 0; k2 < 32; ++k2) {
            float2 v = trow[k2];
            int k = 64 + 2 * k2;
            #pragma unroll
            for (int j = 0; j < 8; ++j) {
                acc[j] = fmaf(v.x, W[k * 8 + j], acc[j]);
                acc[j] = fmaf(v.y, W[(k + 1) * 8 + j], acc[j]);
            }
        }

        float4* Xo = (float4*)(X + (row0 + rl) * GDIM + g * 8);
        Xo[0] = make_float4(acc[0] * INV2PI, acc[1] * INV2PI, acc[2] * INV2PI, acc[3] * INV2PI);
        Xo[1] = make_float4(acc[4] * INV2PI, acc[5] * INV2PI, acc[6] * INV2PI, acc[7] * INV2PI);
    }
}

// ---------------------------------------------------------------------------
// Kernel 2: serial recurrence, r17-proven version VERBATIM (best of 10+
// variants: 86.7 us). Single-stream layout; depth-<=2 broadcast (ror:8);
// tree matvec; row_shl:14 fixup; Estrin activation; all-lane stores.
// Serial launch is INTENTIONAL: rec needs idle SIMDs (r18 fusion = 7x worse).
// ---------------------------------------------------------------------------
__global__ __launch_bounds__(64, 1) void qlstm_rec(
    const float* __restrict__ X,
    const float* __restrict__ Wf, const float* __restrict__ Wi,
    const float* __restrict__ Wu, const float* __restrict__ Wo,
    float* __restrict__ out)
{
    __shared__ float xb[2 * 2 * 128 * 32];   // [buf][batch][ls][col] = 64 KB

    const int lane = threadIdx.x;
    const int p    = lane & 15;
    const int q    = p >> 1;
    const int par  = lane & 1;
    const int s    = lane >> 5;
    const int bb   = (lane >> 4) & 1;
    const int qd   = (lane >> 2) & 3;
    const int gate = s * 2 + par;
    const int b    = blockIdx.x * 2 + bb;
    const int col  = s * 16 + par * 8 + q;

    const bool isq0   = (q == 0);
    const bool loHalf = (lane < 32);
    const bool sB     = (s == 1);
    const bool parB   = (par == 1);

    // per-lane gate weights, permuted to match the broadcast register order
    const float* Wg = (gate == 0) ? Wf : (gate == 1) ? Wi : (gate == 2) ? Wu : Wo;
    float wv[8];
    #pragma unroll
    for (int i = 0; i < 8; ++i)
        wv[i] = Wg[(IN_DIM + (i ^ (qd << 1))) * 8 + q] * INV2PI;

    // activation: act = fmaf(outv, G(outv^2), bbv)
    const bool  isT = (gate == 2);
    const float G0 = isT ? 0.9999014f  : 0.24997535f;
    const float G1 = isT ? -0.3310474f : -0.02069046f;
    const float G2 = isT ? 0.1204402f  : 0.00188188f;
    const float G3 = isT ? -0.0277f    : -0.000108203f;
    const float bbv = isT ? 0.0f : 0.5f;

    const float* g0 = X + (lane >> 3) * SLICE + (lane & 7) * 4
                        + blockIdx.x * 2 * GDIM;
    auto stage = [&](int bi, int qs) {
        #pragma unroll
        for (int j = 0; j < 2; ++j) {
            float* dst = &xb[(bi * 2 + j) * 4096];
            const float* srcb = g0 + j * GDIM + qs * SLICE;
            #pragma unroll
            for (int n = 0; n < 16; ++n)
                gload_lds16(srcb + n * 8 * SLICE, dst + n * 256);
        }
    };

    stage(0, 0);
    asm volatile("s_waitcnt vmcnt(0)" ::: "memory");

    const float* xq0 = &xb[bb * 4096 + col];
    float xv0 = xq0[0];
    float xv1 = xq0[32];
    stage(1, 128);

    float hx = 0.0f, cx = 0.0f;
    const float ONE = 1.0f;
    float* outp = out + b * 8 + q;

    for (int qt = 0; qt < 4; ++qt) {
        const int bi = qt & 1;
        const float* xq = &xb[bi * 8192 + bb * 4096 + col];
        if (qt > 0) {
            asm volatile("s_waitcnt vmcnt(0)" ::: "memory");
            xv0 = xq[0];
            xv1 = xq[32];
            if (qt < 3) stage(1 - bi, (qt + 1) * 128);
        }

        auto qstep = [&](int t, int ls, float& XV) {
            float xv = XV;
            XV = xq[((ls + 2) & 127) * 32];       // lookahead refill (wrap-safe)

            // ---- hx broadcast: 8 DPPs at depth <=2 ----
            float Ba = dppm<0x00>(hx);            // h[2qd]
            float Bb = dppm<0xAA>(hx);            // h[2qd+1]
            float Bc = dppm<0x141>(Ba);           // h[2qd^2]
            float Bd = dppm<0x141>(Bb);           // h[(2qd^2)+1]
            float Be = dppm<0x140>(Ba);           // h[2qd^6]
            float Bf = dppm<0x140>(Bb);           // h[(2qd^6)+1]
            float Bg = dppm<0x128>(Ba);           // h[2qd^4]  (ror:8)
            float Bk = dppm<0x128>(Bb);           // h[(2qd^4)+1]

            // ---- tree matvec (pairing identical to r13) ----
            float A1 = fmaf(Bb, wv[1], fmaf(Ba, wv[0], xv));
            float A2 = fmaf(Bd, wv[3], Bc * wv[2]);
            float A3 = fmaf(Bf, wv[7], Be * wv[6]);
            float A4 = fmaf(Bk, wv[5], Bg * wv[4]);
            float z  = (A1 + A2) + (A3 + A4);

            float cq = __builtin_amdgcn_cosf(z);  // cos(2pi * z')

            // off-path: rcp of own cosine (q=0 lanes use it; clamped vs 0)
            float cc  = fabsf(cq) < 1e-30f ? 1e-30f : cq;
            float rcpc = __builtin_amdgcn_rcpf(cc);

            // ---- prefix product P_q = c0..cq (stride-2 lanes, keep-old=1) ----
            float P = cq * dppk<0x112>(ONE, cq);
            P = P * dppk<0x114>(ONE, P);
            P = P * dppk<0x118>(ONE, P);

            // ---- q=0 output: fullprod via single row_shl:14 ----
            float Pfull = dppm<0x10E>(P);         // p0<-P[14], p1<-P[15]
            float out0  = Pfull * rcpc;
            float outv  = isq0 ? out0 : P;

            // ---- activation (Estrin): act = outv*G(outv^2) + bbv ----
            float u  = outv * outv;
            float u2 = u * u;
            float t1 = fmaf(u, G1, G0);
            float t2 = fmaf(u, G3, G2);
            float G  = fmaf(u2, t2, t1);
            float act = fmaf(outv, G, bbv);

            // ---- gather f,i,u,o for this unit ----
            float n1 = dppm<0xB1>(act);           // other parity, own stream
            auto pr = __builtin_amdgcn_permlane32_swap(
                __float_as_int(act), __float_as_int(act), false, false);
            float sw = __int_as_float(loHalf ? pr[1] : pr[0]);  // act[lane^32]
            float sw2 = dppm<0xB1>(sw);           // other stream, other parity

            float X1 = parB ? n1  : act;          // own-stream even gate
            float X2 = parB ? act : n1;           // own-stream odd gate
            float Y1 = parB ? sw2 : sw;           // other-stream even gate
            float Y2 = parB ? sw  : sw2;          // other-stream odd gate

            float fv = sB ? Y1 : X1;
            float iv = sB ? Y2 : X2;
            float uv = sB ? X1 : Y1;
            float ov = sB ? X2 : Y2;

            // ---- state update ----
            float ncx = fmaf(fv, cx, iv * uv);
            float nhx = ov * tanh_pade(ncx);
            cx = ncx;
            hx = nhx;

            // all lanes store: 4 lanes per (bb,q) write the same value
            __builtin_nontemporal_store(nhx, outp + t * (BATCH * 8));
        };

        #pragma unroll 2
        for (int ls = 0; ls < 128; ls += 2) {
            qstep(qt * 128 + ls,     ls,     xv0);
            qstep(qt * 128 + ls + 1, ls + 1, xv1);
        }
    }

    __builtin_nontemporal_store(hx, out + T_STEPS * BATCH * 8 + b * 8 + q);
    __builtin_nontemporal_store(cx, out + T_STEPS * BATCH * 8 + (BATCH + b) * 8 + q);
}

// ---------------------------------------------------------------------------
extern "C" void kernel_launch(void* const* d_in, const int* in_sizes, int n_in,
                              void* d_out, int out_size, void* d_ws, size_t ws_size,
                              hipStream_t stream) {
    const float* inp = (const float*)d_in[0];
    const float* Wf  = (const float*)d_in[1];
    const float* bf  = (const float*)d_in[2];
    const float* Wi  = (const float*)d_in[3];
    const float* bi  = (const float*)d_in[4];
    const float* Wu  = (const float*)d_in[5];
    const float* bu  = (const float*)d_in[6];
    const float* Wo  = (const float*)d_in[7];
    const float* bo  = (const float*)d_in[8];
    const float* thf = (const float*)d_in[9];
    const float* thi = (const float*)d_in[10];
    const float* thu = (const float*)d_in[11];
    const float* tho = (const float*)d_in[12];

    float* X   = (float*)d_ws;              // (T*B, 32) fp32 = 33.5 MB
    float* out = (float*)d_out;

    qlstm_xproj<<<(T_STEPS * BATCH) / 64, 512, 0, stream>>>(
        inp, Wf, bf, Wi, bi, Wu, bu, Wo, bo, thf, thi, thu, tho, X);

    qlstm_rec<<<BATCH / 2, 64, 0, stream>>>(X, Wf, Wi, Wu, Wo, out);
}

// Round 22
// 125.361 us; speedup vs baseline: 1.0081x; 1.0081x over previous
//
#include <hip/hip_runtime.h>
#include <stdint.h>

#define T_STEPS 512
#define BATCH   512
#define IN_DIM  128
#define GDIM    32   // 4 gates x 8 qubits
#define SLICE   (BATCH * GDIM)   // 16384 floats per time step
#define INV2PI  0.15915494309189535f

typedef float f4 __attribute__((ext_vector_type(4)));

// ---------------------------------------------------------------------------
// DPP helpers. Conventions PROVEN by passing kernels (r2/r8/r11/r13/r17):
//   row_shl:k (0x100|k): dst i <- src i+k (OOB -> 0 with bound_ctrl=1)
//   row_shr:k (0x110|k): dst i <- src i-k
//   row_ror:8 (0x128):   dst i <- src (i+8)&15   (symmetric at 8)
//   row_mirror 0x140: dst i <- src 15-i ; row_half_mirror 0x141: i^7 within 8.
//   quad_perm 0xB1: pair swap (dst i <- src i^1).
// ---------------------------------------------------------------------------
template <int CTRL>
__device__ __forceinline__ float dppm(float x) {
    return __int_as_float(__builtin_amdgcn_mov_dpp(__float_as_int(x), CTRL, 0xF, 0xF, true));
}
template <int CTRL>
__device__ __forceinline__ float dppk(float old, float x) {
    return __int_as_float(__builtin_amdgcn_update_dpp(
        __float_as_int(old), __float_as_int(x), CTRL, 0xF, 0xF, false));
}

// tanh Pade[5/4]: x(945+105u+u^2)/(945+420u+15u^2), u=x^2. err<=5e-5 on [-2.2,2.2].
__device__ __forceinline__ float tanh_pade(float x) {
    float u = x * x;
    float n = fmaf(u, u + 105.0f, 945.0f);
    float d = fmaf(u, fmaf(u, 15.0f, 420.0f), 945.0f);
    return (x * n) * __builtin_amdgcn_rcpf(d);
}

// async global->LDS, 16 bytes per lane: LDS dest = base + lane*16
__device__ __forceinline__ void gload_lds16(const float* g, float* l) {
    __builtin_amdgcn_global_load_lds(
        (const __attribute__((address_space(1))) void*)g,
        (__attribute__((address_space(3))) void*)l, 16, 0, 0);
}

// ---------------------------------------------------------------------------
// Kernel 1: X[row][g] = (inp[row].W_gate[:,q] + b_gate[q] + theta_gate[q])/2pi
// WAVE-SPECIALIZED producer/consumer (r20-proven best of 6 structures:
// 38.5us): 512 threads = 4 producer waves (stage next tile) + 4 consumer
// waves (wave = gate, r13-proven compute). Double-buffered 2x64x130 LDS
// (66.5KB -> 2 blocks/CU). Producers issue tile i+1's loads right after each
// barrier, overlapping consumers' FMA on tile i — memory (~27us) and FMA
// (~14us) legs run on DIFFERENT waves.
// Race check: iter i writes buf[(i+1)&1], reads buf[i&1] (disjoint); the
// per-iter __syncthreads publishes writes and protects re-use one iter later.
// ---------------------------------------------------------------------------
__global__ __launch_bounds__(512) void qlstm_xproj(
    const float* __restrict__ inp,
    const float* __restrict__ Wf, const float* __restrict__ bf,
    const float* __restrict__ Wi, const float* __restrict__ bi,
    const float* __restrict__ Wu, const float* __restrict__ bu,
    const float* __restrict__ Wo, const float* __restrict__ bo,
    const float* __restrict__ thf, const float* __restrict__ thi,
    const float* __restrict__ thu, const float* __restrict__ tho,
    float* __restrict__ X)
{
    __shared__ float tile[2][64 * 130];
    const int tid = threadIdx.x;
    const int t0  = blockIdx.x * 8;          // 8 tiles of 64 rows per block
    const bool producer = (tid < 256);

    if (producer) {
        // prologue: stage tile 0 into buf 0
        const f4* src = (const f4*)(inp + (long long)t0 * 64 * IN_DIM);
        #pragma unroll
        for (int j = 0; j < 8; ++j) {
            int f = tid + j * 256;
            f4 v = __builtin_nontemporal_load(src + f);
            int r = f >> 5, c = (f & 31) << 2;
            float* d = &tile[0][r * 130 + c];
            d[0] = v.x; d[1] = v.y; d[2] = v.z; d[3] = v.w;
        }
    }

    // consumer setup (outside the tile loop)
    const int c0 = tid - 256;
    const int g  = __builtin_amdgcn_readfirstlane(c0 >> 6) & 3;  // consumer wave id
    const int rl = c0 & 63;
    const float* W  = (g == 0) ? Wf : (g == 1) ? Wi : (g == 2) ? Wu : Wo;
    const float* B  = (g == 0) ? bf : (g == 1) ? bi : (g == 2) ? bu : bo;
    const float* TH = (g == 0) ? thf : (g == 1) ? thi : (g == 2) ? thu : tho;
    float binit[8];
    #pragma unroll
    for (int j = 0; j < 8; ++j) binit[j] = B[j] + TH[j];

    __syncthreads();

    for (int i = 0; i < 8; ++i) {
        if (producer) {
            if (i < 7) {   // stage tile i+1 into the other buffer
                const f4* src = (const f4*)(inp + (long long)(t0 + i + 1) * 64 * IN_DIM);
                f4 v[8];
                #pragma unroll
                for (int j = 0; j < 8; ++j)
                    v[j] = __builtin_nontemporal_load(src + tid + j * 256);
                float* buf = tile[(i + 1) & 1];
                #pragma unroll
                for (int j = 0; j < 8; ++j) {
                    int f = tid + j * 256;
                    int r = f >> 5, c = (f & 31) << 2;
                    float* d = &buf[r * 130 + c];
                    d[0] = v[j].x; d[1] = v[j].y; d[2] = v[j].z; d[3] = v[j].w;
                }
            }
        } else {
            float acc[8];
            #pragma unroll
            for (int j = 0; j < 8; ++j) acc[j] = binit[j];

            const float2* trow = (const float2*)&tile[i & 1][rl * 130];
            #pragma unroll 8
            for (int k2 = 0; k2 < 64; ++k2) {
                float2 v = trow[k2];      // ds_read_b64, 2-way alias = free
                int k = 2 * k2;
                #pragma unroll
                for (int j = 0; j < 8; ++j) {
                    acc[j] = fmaf(v.x, W[k * 8 + j], acc[j]);   // uniform -> s_load
                    acc[j] = fmaf(v.y, W[(k + 1) * 8 + j], acc[j]);
                }
            }

            long long row0 = (long long)(t0 + i) * 64;
            float4* Xo = (float4*)(X + (row0 + rl) * GDIM + g * 8);
            Xo[0] = make_float4(acc[0] * INV2PI, acc[1] * INV2PI, acc[2] * INV2PI, acc[3] * INV2PI);
            Xo[1] = make_float4(acc[4] * INV2PI, acc[5] * INV2PI, acc[6] * INV2PI, acc[7] * INV2PI);
        }
        __syncthreads();   // same count on both paths; publishes buf[(i+1)&1]
    }
}

// ---------------------------------------------------------------------------
// Kernel 2: serial recurrence, r17-proven version VERBATIM (best of 10+
// variants: 86.7 us). Single-stream layout; depth-<=2 broadcast (ror:8);
// tree matvec; row_shl:14 fixup; Estrin activation; all-lane stores.
// Serial launch is INTENTIONAL: rec needs idle SIMDs (r18 fusion = 7x worse).
// ---------------------------------------------------------------------------
__global__ __launch_bounds__(64, 1) void qlstm_rec(
    const float* __restrict__ X,
    const float* __restrict__ Wf, const float* __restrict__ Wi,
    const float* __restrict__ Wu, const float* __restrict__ Wo,
    float* __restrict__ out)
{
    __shared__ float xb[2 * 2 * 128 * 32];   // [buf][batch][ls][col] = 64 KB

    const int lane = threadIdx.x;
    const int p    = lane & 15;
    const int q    = p >> 1;
    const int par  = lane & 1;
    const int s    = lane >> 5;
    const int bb   = (lane >> 4) & 1;
    const int qd   = (lane >> 2) & 3;
    const int gate = s * 2 + par;
    const int b    = blockIdx.x * 2 + bb;
    const int col  = s * 16 + par * 8 + q;

    const bool isq0   = (q == 0);
    const bool loHalf = (lane < 32);
    const bool sB     = (s == 1);
    const bool parB   = (par == 1);

    // per-lane gate weights, permuted to match the broadcast register order
    const float* Wg = (gate == 0) ? Wf : (gate == 1) ? Wi : (gate == 2) ? Wu : Wo;
    float wv[8];
    #pragma unroll
    for (int i = 0; i < 8; ++i)
        wv[i] = Wg[(IN_DIM + (i ^ (qd << 1))) * 8 + q] * INV2PI;

    // activation: act = fmaf(outv, G(outv^2), bbv)
    const bool  isT = (gate == 2);
    const float G0 = isT ? 0.9999014f  : 0.24997535f;
    const float G1 = isT ? -0.3310474f : -0.02069046f;
    const float G2 = isT ? 0.1204402f  : 0.00188188f;
    const float G3 = isT ? -0.0277f    : -0.000108203f;
    const float bbv = isT ? 0.0f : 0.5f;

    const float* g0 = X + (lane >> 3) * SLICE + (lane & 7) * 4
                        + blockIdx.x * 2 * GDIM;
    auto stage = [&](int bi, int qs) {
        #pragma unroll
        for (int j = 0; j < 2; ++j) {
            float* dst = &xb[(bi * 2 + j) * 4096];
            const float* srcb = g0 + j * GDIM + qs * SLICE;
            #pragma unroll
            for (int n = 0; n < 16; ++n)
                gload_lds16(srcb + n * 8 * SLICE, dst + n * 256);
        }
    };

    stage(0, 0);
    asm volatile("s_waitcnt vmcnt(0)" ::: "memory");

    const float* xq0 = &xb[bb * 4096 + col];
    float xv0 = xq0[0];
    float xv1 = xq0[32];
    stage(1, 128);

    float hx = 0.0f, cx = 0.0f;
    const float ONE = 1.0f;
    float* outp = out + b * 8 + q;

    for (int qt = 0; qt < 4; ++qt) {
        const int bi = qt & 1;
        const float* xq = &xb[bi * 8192 + bb * 4096 + col];
        if (qt > 0) {
            asm volatile("s_waitcnt vmcnt(0)" ::: "memory");
            xv0 = xq[0];
            xv1 = xq[32];
            if (qt < 3) stage(1 - bi, (qt + 1) * 128);
        }

        auto qstep = [&](int t, int ls, float& XV) {
            float xv = XV;
            XV = xq[((ls + 2) & 127) * 32];       // lookahead refill (wrap-safe)

            // ---- hx broadcast: 8 DPPs at depth <=2 ----
            float Ba = dppm<0x00>(hx);            // h[2qd]
            float Bb = dppm<0xAA>(hx);            // h[2qd+1]
            float Bc = dppm<0x141>(Ba);           // h[2qd^2]
            float Bd = dppm<0x141>(Bb);           // h[(2qd^2)+1]
            float Be = dppm<0x140>(Ba);           // h[2qd^6]
            float Bf = dppm<0x140>(Bb);           // h[(2qd^6)+1]
            float Bg = dppm<0x128>(Ba);           // h[2qd^4]  (ror:8)
            float Bk = dppm<0x128>(Bb);           // h[(2qd^4)+1]

            // ---- tree matvec (pairing identical to r13) ----
            float A1 = fmaf(Bb, wv[1], fmaf(Ba, wv[0], xv));
            float A2 = fmaf(Bd, wv[3], Bc * wv[2]);
            float A3 = fmaf(Bf, wv[7], Be * wv[6]);
            float A4 = fmaf(Bk, wv[5], Bg * wv[4]);
            float z  = (A1 + A2) + (A3 + A4);

            float cq = __builtin_amdgcn_cosf(z);  // cos(2pi * z')

            // off-path: rcp of own cosine (q=0 lanes use it; clamped vs 0)
            float cc  = fabsf(cq) < 1e-30f ? 1e-30f : cq;
            float rcpc = __builtin_amdgcn_rcpf(cc);

            // ---- prefix product P_q = c0..cq (stride-2 lanes, keep-old=1) ----
            float P = cq * dppk<0x112>(ONE, cq);
            P = P * dppk<0x114>(ONE, P);
            P = P * dppk<0x118>(ONE, P);

            // ---- q=0 output: fullprod via single row_shl:14 ----
            float Pfull = dppm<0x10E>(P);         // p0<-P[14], p1<-P[15]
            float out0  = Pfull * rcpc;
            float outv  = isq0 ? out0 : P;

            // ---- activation (Estrin): act = outv*G(outv^2) + bbv ----
            float u  = outv * outv;
            float u2 = u * u;
            float t1 = fmaf(u, G1, G0);
            float t2 = fmaf(u, G3, G2);
            float G  = fmaf(u2, t2, t1);
            float act = fmaf(outv, G, bbv);

            // ---- gather f,i,u,o for this unit ----
            float n1 = dppm<0xB1>(act);           // other parity, own stream
            auto pr = __builtin_amdgcn_permlane32_swap(
                __float_as_int(act), __float_as_int(act), false, false);
            float sw = __int_as_float(loHalf ? pr[1] : pr[0]);  // act[lane^32]
            float sw2 = dppm<0xB1>(sw);           // other stream, other parity

            float X1 = parB ? n1  : act;          // own-stream even gate
            float X2 = parB ? act : n1;           // own-stream odd gate
            float Y1 = parB ? sw2 : sw;           // other-stream even gate
            float Y2 = parB ? sw  : sw2;          // other-stream odd gate

            float fv = sB ? Y1 : X1;
            float iv = sB ? Y2 : X2;
            float uv = sB ? X1 : Y1;
            float ov = sB ? X2 : Y2;

            // ---- state update ----
            float ncx = fmaf(fv, cx, iv * uv);
            float nhx = ov * tanh_pade(ncx);
            cx = ncx;
            hx = nhx;

            // all lanes store: 4 lanes per (bb,q) write the same value
            __builtin_nontemporal_store(nhx, outp + t * (BATCH * 8));
        };

        #pragma unroll 2
        for (int ls = 0; ls < 128; ls += 2) {
            qstep(qt * 128 + ls,     ls,     xv0);
            qstep(qt * 128 + ls + 1, ls + 1, xv1);
        }
    }

    __builtin_nontemporal_store(hx, out + T_STEPS * BATCH * 8 + b * 8 + q);
    __builtin_nontemporal_store(cx, out + T_STEPS * BATCH * 8 + (BATCH + b) * 8 + q);
}

// ---------------------------------------------------------------------------
extern "C" void kernel_launch(void* const* d_in, const int* in_sizes, int n_in,
                              void* d_out, int out_size, void* d_ws, size_t ws_size,
                              hipStream_t stream) {
    const float* inp = (const float*)d_in[0];
    const float* Wf  = (const float*)d_in[1];
    const float* bf  = (const float*)d_in[2];
    const float* Wi  = (const float*)d_in[3];
    const float* bi  = (const float*)d_in[4];
    const float* Wu  = (const float*)d_in[5];
    const float* bu  = (const float*)d_in[6];
    const float* Wo  = (const float*)d_in[7];
    const float* bo  = (const float*)d_in[8];
    const float* thf = (const float*)d_in[9];
    const float* thi = (const float*)d_in[10];
    const float* thu = (const float*)d_in[11];
    const float* tho = (const float*)d_in[12];

    float* X   = (float*)d_ws;              // (T*B, 32) fp32 = 33.5 MB
    float* out = (float*)d_out;

    qlstm_xproj<<<(T_STEPS * BATCH) / (64 * 8), 512, 0, stream>>>(
        inp, Wf, bf, Wi, bi, Wu, bu, Wo, bo, thf, thi, thu, tho, X);

    qlstm_rec<<<BATCH / 2, 64, 0, stream>>>(X, Wf, Wi, Wu, Wo, out);
}